// Round 4
// baseline (299.373 us; speedup 1.0000x reference)
//
#include <hip/hip_runtime.h>
#include <hip/hip_bf16.h>

// Problem constants
#define Bb 8
#define Ss 8192
#define Dd 256             // DIN == DH == 256
#define Mm (Bb * Ss)       // 65536 rows
#define Nn 512             // 2*DH output cols of the GEMM
#define NCHUNK 128
#define CLEN (Ss / NCHUNK) // 64
#define TSW 36             // Ts row stride (u32): 32 + 4 pad, 16B-aligned rows

typedef __hip_bfloat16 bf16;
typedef __attribute__((ext_vector_type(8))) short short8;
typedef __attribute__((ext_vector_type(4))) float f32x4;

__device__ __forceinline__ void load_lds16(const void* g, void* l) {
  __builtin_amdgcn_global_load_lds(
      (const __attribute__((address_space(1))) void*)g,
      (__attribute__((address_space(3))) void*)l, 16, 0, 0);
}

// ---------------------------------------------------------------------------
// f32 -> bf16 convert, both weight matrices in one launch
// ---------------------------------------------------------------------------
__global__ __launch_bounds__(256) void cvt_weights(
    const float* __restrict__ inA, const float* __restrict__ inB,
    bf16* __restrict__ outA, bf16* __restrict__ outB, long n4each) {
  long i = (long)blockIdx.x * blockDim.x + threadIdx.x;
  const float* in = inA;
  bf16* out = outA;
  if (i >= n4each) {
    in = inB;
    out = outB;
    i -= n4each;
  }
  if (i >= n4each) return;
  const float4 v = ((const float4*)in)[i];
  union { ushort4 u; bf16 h[4]; } o;
  o.h[0] = __float2bfloat16(v.x);
  o.h[1] = __float2bfloat16(v.y);
  o.h[2] = __float2bfloat16(v.z);
  o.h[3] = __float2bfloat16(v.w);
  ((ushort4*)out)[i] = o.u;
}

// ---------------------------------------------------------------------------
// Pointwise: a = sigmoid(-gate), v = sigmoid(gate) * g(hidden)
// ---------------------------------------------------------------------------
__device__ __forceinline__ void av_from_gh(float gate, float hid, float& a,
                                           float& v) {
  gate = fminf(fmaxf(gate, -20.f), 20.f);
  float eg = __expf(gate);
  a = 1.f / (1.f + eg);   // sigmoid(-gate) = 1 - z
  float z = eg * a;       // sigmoid(gate)
  float eh = __expf(fminf(fmaxf(hid, -20.f), 0.f));
  float sig = eh / (1.f + eh);
  float gfun = (hid >= 0.f) ? (hid + 0.5f) : sig;
  v = z * gfun;
}

__device__ __forceinline__ unsigned pack_av(float a, float v) {
  union { bf16 h[2]; unsigned u; } o;
  o.h[0] = __float2bfloat16(a);
  o.h[1] = __float2bfloat16(v);
  return o.u;
}

// ---------------------------------------------------------------------------
// Fused GEMM + bias + pointwise + per-chunk scan summaries.
//
// v5: BARRIER-FREE K-loop.
//  * W slice (64 rows x 256 K = 32 KB) loaded to LDS ONCE (single barrier),
//    XOR-swizzled so ds_read_b128 fragment reads are ~conflict-free.
//  * A streams straight from global memory into MFMA registers
//    (global_load_dwordx4 per fragment, reg double-buffer) -- no A-LDS,
//    no staging DMA, no in-loop barriers. Waves free-run; latency is hidden
//    by TLP (32 KB LDS -> 4-5 blocks/CU) instead of a barrier convoy.
//  * Block = 128 rows x 64 cols (32 gate d + 32 hidden d of pair-block cb).
//    Wave = 32 rows x 64 cols = 2 mt x 4 nt frags, 8 MFMA / K-step.
//  * Grid 4096 = 8 cb x 512 bt, XCD-bijective swizzle: one XCD owns all
//    8 cb of 64 consecutive bt -> X panel HBM-fetched once per XCD.
//  * AV layout [cb 8][row Mm][32 d] u32, dense coalesced stores via Ts.
// ---------------------------------------------------------------------------
template <bool F32A>
__global__ __launch_bounds__(256, F32A ? 3 : 4) void gemm_av_fused(
    const void* __restrict__ Xv, const bf16* __restrict__ W,
    const float* __restrict__ bias, unsigned* __restrict__ AV,
    float2* __restrict__ AVs) {
  __shared__ __align__(16) char sm[32768];
  bf16* Bs = (bf16*)sm;          // [64 rows][256 k], kc swizzled
  unsigned* Ts = (unsigned*)sm;  // post-K-loop overlay: [128 t][TSW] u32

  const int tid = threadIdx.x;
  const int w = tid >> 6;
  const int l = tid & 63;
  const int fl = l & 15;
  const int q = l >> 4;

  // XCD-bijective swizzle: xcd owns lin [xcd*512,+512) = bt in [xcd*64,+64)
  const int id = blockIdx.x;
  const int lin = ((id & 7) << 9) | (id >> 3);
  const int cb = lin & 7;              // pair-channel block 0..7 (32 d each)
  const int bt = lin >> 3;             // M-tile 0..511 (128 rows)
  const long rowBase = (long)bt * 128;

  // ---- stage W slice once: rows 0..31 = gate d [cb*32,+32), 32..63 = hidden
  {
#pragma unroll
    for (int it = 0; it < 8; it++) {
      const int L = it * 256 + tid;
      const int row = L >> 5;                       // 0..63
      const int kc = (L & 31) ^ (row & 7);          // 8-bf16 chunk, swizzled
      const int grow =
          (row < 32) ? (cb * 32 + row) : (256 + cb * 32 + (row - 32));
      load_lds16(W + (long)grow * 256 + kc * 8,
                 (char*)sm + (it * 256 + w * 64) * 16);
    }
  }
  asm volatile("s_waitcnt vmcnt(0)" ::: "memory");
  __syncthreads();  // the ONLY barrier before the epilogue

  // ---- A pointers (per-lane, direct-from-global fragments)
  const float* Xf = (const float*)Xv;
  const bf16* Xb = (const bf16*)Xv;
  const float* aPF[2];
  const bf16* aPB[2];
#pragma unroll
  for (int mt = 0; mt < 2; mt++) {
    const long arow = rowBase + w * 32 + 16 * mt + fl;
    aPF[mt] = Xf + arow * 256 + q * 8;
    aPB[mt] = Xb + arow * 256 + q * 8;
  }
  const int bswz = fl & 7;
  int bRow[4];
#pragma unroll
  for (int nt = 0; nt < 4; nt++) bRow[nt] = (nt * 16 + fl) * 256;

  f32x4 acc[2][4];
#pragma unroll
  for (int i = 0; i < 2; i++)
#pragma unroll
    for (int j = 0; j < 4; j++) acc[i][j] = (f32x4)0.0f;

  // reg double-buffers
  short8 aB_[2][2];   // bf16 path
  float4 aR[2][2][2]; // f32 path (raw, converted at use)
  short8 bF[2][4];

  auto loadA = [&](int bi, int ks) {
    if constexpr (F32A) {
#pragma unroll
      for (int mt = 0; mt < 2; mt++) {
        aR[bi][mt][0] = *(const float4*)(aPF[mt] + ks * 32);
        aR[bi][mt][1] = *(const float4*)(aPF[mt] + ks * 32 + 4);
      }
    } else {
#pragma unroll
      for (int mt = 0; mt < 2; mt++)
        aB_[bi][mt] = *(const short8*)(aPB[mt] + ks * 32);
    }
  };
  auto loadB = [&](int bi, int ks) {
#pragma unroll
    for (int nt = 0; nt < 4; nt++)
      bF[bi][nt] =
          *(const short8*)(Bs + bRow[nt] + (((ks * 4 + q) ^ bswz) * 8));
  };
  auto getA = [&](int bi, int mt) -> short8 {
    if constexpr (F32A) {
      const float4 u0 = aR[bi][mt][0];
      const float4 u1 = aR[bi][mt][1];
      const float vals[8] = {u0.x, u0.y, u0.z, u0.w, u1.x, u1.y, u1.z, u1.w};
      short8 r;
#pragma unroll
      for (int i = 0; i < 8; i++) {
        union { bf16 h; short s; } t;
        t.h = __float2bfloat16(vals[i]);
        r[i] = t.s;
      }
      return r;
    } else {
      return aB_[bi][mt];
    }
  };

  // ---- barrier-free K-loop (fully unrolled, reg dbuf, compiler waitcnts)
  loadA(0, 0);
  loadB(0, 0);
#pragma unroll
  for (int ks = 0; ks < 8; ks++) {
    const int bi = ks & 1;
    if (ks < 7) {
      loadA(bi ^ 1, ks + 1);
      loadB(bi ^ 1, ks + 1);
    }
    const short8 a0 = getA(bi, 0);
    const short8 a1 = getA(bi, 1);
#pragma unroll
    for (int nt = 0; nt < 4; nt++) {
      acc[0][nt] = __builtin_amdgcn_mfma_f32_16x16x32_bf16(a0, bF[bi][nt],
                                                           acc[0][nt], 0, 0, 0);
      acc[1][nt] = __builtin_amdgcn_mfma_f32_16x16x32_bf16(a1, bF[bi][nt],
                                                           acc[1][nt], 0, 0, 0);
    }
  }

  // ---- Epilogue: bias + pointwise + pack (registers only)
  float bg[2], bh[2];
#pragma unroll
  for (int p = 0; p < 2; p++) {
    const int d = cb * 32 + 16 * p + fl;
    bg[p] = bias[d];
    bh[p] = bias[256 + d];
  }
  unsigned pk[2][2][4];
#pragma unroll
  for (int mt = 0; mt < 2; mt++)
#pragma unroll
    for (int p = 0; p < 2; p++)
#pragma unroll
      for (int r = 0; r < 4; r++) {
        float a, v;
        av_from_gh(acc[mt][p][r] + bg[p], acc[mt][p + 2][r] + bh[p], a, v);
        pk[mt][p][r] = pack_av(a, v);
      }

  __syncthreads();  // all waves done reading Bs -> safe to overlay Ts

  // ---- Ts transpose: t = w*32 + 16mt + 4q + r, col = 16p + fl
#pragma unroll
  for (int mt = 0; mt < 2; mt++)
#pragma unroll
    for (int p = 0; p < 2; p++)
#pragma unroll
      for (int r = 0; r < 4; r++)
        Ts[(w * 32 + 16 * mt + 4 * q + r) * TSW + 16 * p + fl] =
            pk[mt][p][r];
  __syncthreads();

  // ---- dense AV store: [128 rows][32 d] u32 = 16 KB, 1KB/wave contiguous
  {
    unsigned* dst = AV + ((long)cb * Mm + rowBase) * 32;
#pragma unroll
    for (int it = 0; it < 4; it++) {
      const int idx = it * 256 + tid;
      const int t = idx >> 3;
      const int d4 = idx & 7;
      *(uint4*)(dst + t * 32 + d4 * 4) = *(const uint4*)(Ts + t * TSW + d4 * 4);
    }
  }

  // ---- per-chunk scan summaries: 64 threads, 2 chunks x 32 d
  if (tid < 64) {
    const int h = tid >> 5;
    const int dl = tid & 31;
    float A = 1.f, H = 0.f;
#pragma unroll 8
    for (int t = 0; t < 64; t++) {
      const unsigned p = Ts[(64 * h + t) * TSW + dl];
      const float a = __uint_as_float((p & 0xffffu) << 16);
      const float v = __uint_as_float(p & 0xffff0000u);
      A *= a;
      H = a * H + v;
    }
    AVs[((long)bt * 2 + h) * 256 + cb * 32 + dl] = make_float2(A, H);
  }
}

// ---------------------------------------------------------------------------
// Final scan. Prologue folds this chunk's prefix from the (L3-hot, 2MB)
// chunk-summary table (independent loads). WRITE_BF16 ? bf16 : f32 stream.
// AV layout: [cb 8][row][32 d] u32 (matches gemm's dense writes).
// ---------------------------------------------------------------------------
template <bool WRITE_BF16>
__global__ __launch_bounds__(256) void scan_final(
    const unsigned* __restrict__ AV, const float2* __restrict__ AVs,
    bf16* __restrict__ OutB, float* __restrict__ OutF,
    float* __restrict__ Hlast) {
  const int d = threadIdx.x;
  const int c = blockIdx.x % NCHUNK;
  const int b = blockIdx.x / NCHUNK;

  float h = 0.5f;  // h0 = g(0) = 0.5
#pragma unroll 4
  for (int j = 0; j < c; j++) {
    const float2 av = AVs[((long)b * NCHUNK + j) * 256 + d];
    h = av.x * h + av.y;
  }

  const long row0 = (long)b * Ss + (long)c * CLEN;
  const unsigned* src = AV + (long)(d >> 5) * Mm * 32 + (d & 31);
  long obase = row0 * 256 + d;
#pragma unroll 8
  for (int t = 0; t < CLEN; t++) {
    const unsigned p = src[(row0 + t) * 32];
    const float a = __uint_as_float((p & 0xffffu) << 16);
    const float v = __uint_as_float(p & 0xffff0000u);
    h = a * h + v;
    if (WRITE_BF16)
      OutB[obase] = __float2bfloat16(h);
    else
      OutF[obase] = h;
    obase += 256;
  }
  if (c == NCHUNK - 1) Hlast[b * 256 + d] = h;
}

// ---------------------------------------------------------------------------
extern "C" void kernel_launch(void* const* d_in, const int* in_sizes, int n_in,
                              void* d_out, int out_size, void* d_ws,
                              size_t ws_size, hipStream_t stream) {
  const float* x = (const float*)d_in[0];
  const float* W0f = (const float*)d_in[1];
  const float* b0 = (const float*)d_in[2];
  const float* W1f = (const float*)d_in[3];
  const float* b1 = (const float*)d_in[4];

  float* outF = (float*)d_out;              // out1 (f32), Mm*256 elements
  float* hlast = outF + (long)Mm * 256;     // h: (2,8,1,256) f32
  // d_out's first 32 MiB doubles as bf16 scratch for X1 (dead before the
  // final f32 out-write overwrites it; ordering is stream-sequential).
  bf16* X1b = (bf16*)d_out;

  char* ws = (char*)d_ws;
  unsigned* AV = (unsigned*)ws;                      // 8*Mm*32 u32 = 64 MiB
  bf16* W0b = (bf16*)(ws + (long)Mm * 256 * 4);      // 512*256 bf16
  bf16* W1b = W0b + (long)Nn * Dd;
  float2* AVs = (float2*)(W1b + (long)Nn * Dd);      // [Bb*NCHUNK][256] = 2 MiB

  const dim3 gemmGrid(4096);  // 1-D, XCD-bijective swizzle decoded in-kernel
  const dim3 blk(256);

  // Convert both weight matrices to bf16 in one launch
  const long n4w = (long)Nn * Dd / 4;
  cvt_weights<<<dim3((2 * n4w + 255) / 256), blk, 0, stream>>>(W0f, W1f, W0b,
                                                               W1b, n4w);

  // Layer 0 (A = f32 x, loaded direct to regs, converted at use)
  gemm_av_fused<true><<<gemmGrid, blk, 0, stream>>>(x, W0b, b0, AV, AVs);
  scan_final<true><<<dim3(Bb * NCHUNK), blk, 0, stream>>>(AV, AVs, X1b,
                                                          nullptr, hlast);

  // Layer 1 (A = bf16 X1 in d_out scratch)
  gemm_av_fused<false><<<gemmGrid, blk, 0, stream>>>(X1b, W1b, b1, AV, AVs);
  scan_final<false><<<dim3(Bb * NCHUNK), blk, 0, stream>>>(
      AV, AVs, nullptr, outF, hlast + Bb * 256);
}

// Round 5
// 264.497 us; speedup vs baseline: 1.1319x; 1.1319x over previous
//
#include <hip/hip_runtime.h>
#include <hip/hip_bf16.h>

// Problem constants
#define Bb 8
#define Ss 8192
#define Dd 256             // DIN == DH == 256
#define Mm (Bb * Ss)       // 65536 rows
#define Nn 512             // 2*DH output cols of the GEMM
#define NCHUNK 128
#define CLEN (Ss / NCHUNK) // 64
#define TSP 68             // Ts row stride (u32): 64 + 4 pad

typedef __hip_bfloat16 bf16;
typedef __attribute__((ext_vector_type(8))) short short8;
typedef __attribute__((ext_vector_type(4))) float f32x4;

// ---------------------------------------------------------------------------
// f32 -> bf16 convert, both weight matrices in one launch
// ---------------------------------------------------------------------------
__global__ __launch_bounds__(256) void cvt_weights(
    const float* __restrict__ inA, const float* __restrict__ inB,
    bf16* __restrict__ outA, bf16* __restrict__ outB, long n4each) {
  long i = (long)blockIdx.x * blockDim.x + threadIdx.x;
  const float* in = inA;
  bf16* out = outA;
  if (i >= n4each) {
    in = inB;
    out = outB;
    i -= n4each;
  }
  if (i >= n4each) return;
  const float4 v = ((const float4*)in)[i];
  union { ushort4 u; bf16 h[4]; } o;
  o.h[0] = __float2bfloat16(v.x);
  o.h[1] = __float2bfloat16(v.y);
  o.h[2] = __float2bfloat16(v.z);
  o.h[3] = __float2bfloat16(v.w);
  ((ushort4*)out)[i] = o.u;
}

// ---------------------------------------------------------------------------
// Pointwise: a = sigmoid(-gate), v = sigmoid(gate) * g(hidden)
// ---------------------------------------------------------------------------
__device__ __forceinline__ void av_from_gh(float gate, float hid, float& a,
                                           float& v) {
  gate = fminf(fmaxf(gate, -20.f), 20.f);
  float eg = __expf(gate);
  a = 1.f / (1.f + eg);   // sigmoid(-gate) = 1 - z
  float z = eg * a;       // sigmoid(gate)
  float eh = __expf(fminf(fmaxf(hid, -20.f), 0.f));
  float sig = eh / (1.f + eh);
  float gfun = (hid >= 0.f) ? (hid + 0.5f) : sig;
  v = z * gfun;
}

__device__ __forceinline__ unsigned pack_av(float a, float v) {
  union { bf16 h[2]; unsigned u; } o;
  o.h[0] = __float2bfloat16(a);
  o.h[1] = __float2bfloat16(v);
  return o.u;
}

// ---------------------------------------------------------------------------
// Fused GEMM + bias + pointwise + per-chunk scan summaries.
//
// v6: REG-STAGED staging (global->VGPR->ds_write), no global_load_lds.
//  * T14 split: global loads for tile ks+2 issued at iter ks; ds_write of
//    tile ks+1 (into the buffer NOT being read) happens same iter -> one
//    barrier per K-step, loads get ~1 full iteration of latency cover,
//    and the LDS-DMA engine (the one component common to v1-v4, all pinned
//    at ~75us) is out of the loop entirely.
//  * Layer 0 converts f32->bf16 once at stage time (in regs, before
//    ds_write): LDS is bf16 for both layers (32 KB total), no per-fragment
//    conversion, no separate X-convert pass.
//  * Tile/readers/epilogue identical to v4 (proven): block (cb,bt) =
//    128 rows x (64 gate + 64 hidden) of pair-block cb; wave 64x64;
//    16 MFMA / K-step; XOR-swizzled LDS; dense coalesced AV stores.
// ---------------------------------------------------------------------------
template <bool F32A>
__global__ __launch_bounds__(256, 3) void gemm_av_fused(
    const void* __restrict__ Xv, const bf16* __restrict__ W,
    const float* __restrict__ bias, unsigned* __restrict__ AV,
    float2* __restrict__ AVs) {
  __shared__ __align__(16) char sm[32768];
  bf16* Ab[2] = {(bf16*)sm, (bf16*)(sm + 8192)};
  bf16* Bbf[2] = {(bf16*)(sm + 16384), (bf16*)(sm + 24576)};
  unsigned* Ts = (unsigned*)sm;  // post-K-loop overlay: [64 t][TSP] u32

  const int tid = threadIdx.x;
  const int w = tid >> 6;
  const int l = tid & 63;
  const int fl = l & 15;
  const int q = l >> 4;

  // XCD-bijective swizzle: xcd owns lin [xcd*256,+256) = bt in [xcd*64,+64)
  const int id = blockIdx.x;
  const int lin = ((id & 7) << 8) | (id >> 3);
  const int cb = lin & 3;              // paired-channel block 0..3
  const int bt = lin >> 2;             // M-tile 0..511
  const long rowBase = (long)bt * 128;
  const int wrow = (w >> 1) * 64;
  const int wc = (w & 1) * 32;

  const float* Xf = (const float*)Xv;
  const bf16* Xb = (const bf16*)Xv;

  // ---- staging addresses (hoisted). Thread covers 2 (row,kq) slots:
  //      idx = c*256+tid -> row = idx>>2 (0..127), kq = idx&3 (8-bf16 chunk).
  //      LDS layout [row][32 k], chunk swizzled: kq' = kq ^ ((row>>1)&3).
  const float* aSF[2];
  const bf16* aSB[2];
  const bf16* bS[2];
  int ldsOff[2];
#pragma unroll
  for (int c = 0; c < 2; c++) {
    const int idx = c * 256 + tid;
    const int row = idx >> 2;
    const int kq = idx & 3;
    ldsOff[c] = row * 32 + (kq ^ ((row >> 1) & 3)) * 8;
    aSF[c] = Xf + (rowBase + row) * 256 + kq * 8;
    aSB[c] = Xb + (rowBase + row) * 256 + kq * 8;
    const int grow = (row < 64) ? (cb * 64 + row) : (192 + cb * 64 + row);
    bS[c] = W + (long)grow * 256 + kq * 8;
  }

  // staging registers (tile in flight)
  short8 aReg[2], bReg[2];
  float4 aF[2][2];

  auto loadG = [&](int ks) {
    if constexpr (F32A) {
#pragma unroll
      for (int c = 0; c < 2; c++) {
        aF[c][0] = *(const float4*)(aSF[c] + ks * 32);
        aF[c][1] = *(const float4*)(aSF[c] + ks * 32 + 4);
      }
    } else {
#pragma unroll
      for (int c = 0; c < 2; c++)
        aReg[c] = *(const short8*)(aSB[c] + ks * 32);
    }
#pragma unroll
    for (int c = 0; c < 2; c++)
      bReg[c] = *(const short8*)(bS[c] + ks * 32);
  };
  auto writeL = [&](int bi) {
#pragma unroll
    for (int c = 0; c < 2; c++) {
      short8 av_;
      if constexpr (F32A) {
        const float vals[8] = {aF[c][0].x, aF[c][0].y, aF[c][0].z, aF[c][0].w,
                               aF[c][1].x, aF[c][1].y, aF[c][1].z, aF[c][1].w};
#pragma unroll
        for (int i = 0; i < 8; i++) {
          union { bf16 h; short s; } t;
          t.h = __float2bfloat16(vals[i]);
          av_[i] = t.s;
        }
      } else {
        av_ = aReg[c];
      }
      *(short8*)(Ab[bi] + ldsOff[c]) = av_;
    }
#pragma unroll
    for (int c = 0; c < 2; c++)
      *(short8*)(Bbf[bi] + ldsOff[c]) = bReg[c];
  };

  // ---- fragment LDS offsets (hoisted, swizzle-matched, conflict-free)
  int aOff[4], bOff[4];
#pragma unroll
  for (int mt = 0; mt < 4; mt++) {
    const int row = wrow + 16 * mt + fl;
    aOff[mt] = row * 32 + (q ^ ((row >> 1) & 3)) * 8;
  }
#pragma unroll
  for (int nt = 0; nt < 4; nt++) {
    const int row =
        (nt < 2) ? (wc + 16 * nt + fl) : (64 + wc + 16 * (nt - 2) + fl);
    bOff[nt] = row * 32 + (q ^ ((row >> 1) & 3)) * 8;
  }

  f32x4 acc[4][4];
#pragma unroll
  for (int i = 0; i < 4; i++)
#pragma unroll
    for (int j = 0; j < 4; j++) acc[i][j] = (f32x4)0.0f;

  // ---- K-loop: reg-staged, ONE barrier per step.
  // Invariant at top of iter ks: buf[ks&1] holds tile ks (all threads);
  // staging regs hold tile ks+1's global loads (in flight or landed).
  loadG(0);
  writeL(0);        // compiler inserts the vmcnt waits for the reg deps
  loadG(1);
  __syncthreads();  // buf0 visible (prologue drain is fine here)
#pragma unroll
  for (int ks = 0; ks < 8; ks++) {
    const int bi = ks & 1;
    short8 af[4], bf_[4];
#pragma unroll
    for (int mt = 0; mt < 4; mt++)
      af[mt] = *(const short8*)(Ab[bi] + aOff[mt]);
#pragma unroll
    for (int nt = 0; nt < 4; nt++)
      bf_[nt] = *(const short8*)(Bbf[bi] + bOff[nt]);
    if (ks < 7) writeL(bi ^ 1);   // tile ks+1 -> other buffer (no conflict
                                  // with concurrent reads of buf[bi])
    if (ks < 6) loadG(ks + 2);    // issue next-next tile's global loads
#pragma unroll
    for (int mt = 0; mt < 4; mt++)
#pragma unroll
      for (int nt = 0; nt < 4; nt++)
        acc[mt][nt] = __builtin_amdgcn_mfma_f32_16x16x32_bf16(
            af[mt], bf_[nt], acc[mt][nt], 0, 0, 0);
    asm volatile("s_waitcnt lgkmcnt(0)" ::: "memory");  // my ds r/w done
    __builtin_amdgcn_s_barrier();  // everyone's reads of bi + writes of bi^1
  }

  // ---- Epilogue: bias + pointwise + pack (registers only)
  float bg[2], bh[2];
#pragma unroll
  for (int p = 0; p < 2; p++) {
    const int d = cb * 64 + wc + 16 * p + fl;
    bg[p] = bias[d];
    bh[p] = bias[256 + d];
  }
  unsigned pk[4][2][4];
#pragma unroll
  for (int mt = 0; mt < 4; mt++)
#pragma unroll
    for (int p = 0; p < 2; p++)
#pragma unroll
      for (int r = 0; r < 4; r++) {
        float a, v;
        av_from_gh(acc[mt][p][r] + bg[p], acc[mt][p + 2][r] + bh[p], a, v);
        pk[mt][p][r] = pack_av(a, v);
      }

  // ---- Two 64-row halves through LDS transpose:
  //      dense coalesced AV stores + per-chunk scan summaries
#pragma unroll
  for (int h = 0; h < 2; h++) {
    if ((w >> 1) == h) {
#pragma unroll
      for (int mt = 0; mt < 4; mt++)
#pragma unroll
        for (int p = 0; p < 2; p++)
#pragma unroll
          for (int r = 0; r < 4; r++)
            Ts[(16 * mt + 4 * q + r) * TSP + wc + 16 * p + fl] = pk[mt][p][r];
    }
    __syncthreads();
    // dense AV half-tile: [64 rows][64 d] u32 -> 1KB/wave contiguous stores
    {
      unsigned* dst = AV + ((long)cb * Mm + rowBase + h * 64) * 64;
#pragma unroll
      for (int j = 0; j < 4; j++) {
        const int idx = j * 256 + tid;
        const int t = idx >> 4;
        const int d4 = idx & 15;
        const uint4 val = *(const uint4*)(Ts + t * TSP + d4 * 4);
        *(uint4*)(dst + 4 * idx) = val;
      }
    }
    if (tid < 64) {
      float A = 1.f, H = 0.f;
#pragma unroll 8
      for (int t = 0; t < 64; t++) {
        const unsigned p = Ts[t * TSP + tid];
        const float a = __uint_as_float((p & 0xffffu) << 16);
        const float v = __uint_as_float(p & 0xffff0000u);
        A *= a;
        H = a * H + v;
      }
      const long cg = (long)(bt >> 6) * NCHUNK + ((bt & 63) << 1) + h;
      AVs[cg * 256 + cb * 64 + tid] = make_float2(A, H);
    }
    __syncthreads();
  }
}

// ---------------------------------------------------------------------------
// Final scan. Prologue folds this chunk's prefix from the (L3-hot, 2MB)
// chunk-summary table (independent loads). WRITE_BF16 ? bf16 : f32 stream.
// AV layout: [cb 4][row][64 d] u32 (matches gemm's dense writes).
// ---------------------------------------------------------------------------
template <bool WRITE_BF16>
__global__ __launch_bounds__(256) void scan_final(
    const unsigned* __restrict__ AV, const float2* __restrict__ AVs,
    bf16* __restrict__ OutB, float* __restrict__ OutF,
    float* __restrict__ Hlast) {
  const int d = threadIdx.x;
  const int c = blockIdx.x % NCHUNK;
  const int b = blockIdx.x / NCHUNK;

  float h = 0.5f;  // h0 = g(0) = 0.5
#pragma unroll 4
  for (int j = 0; j < c; j++) {
    const float2 av = AVs[((long)b * NCHUNK + j) * 256 + d];
    h = av.x * h + av.y;
  }

  const long row0 = (long)b * Ss + (long)c * CLEN;
  const unsigned* src = AV + (long)(d >> 6) * Mm * 64 + (d & 63);
  long obase = row0 * 256 + d;
#pragma unroll 8
  for (int t = 0; t < CLEN; t++) {
    const unsigned p = src[(row0 + t) * 64];
    const float a = __uint_as_float((p & 0xffffu) << 16);
    const float v = __uint_as_float(p & 0xffff0000u);
    h = a * h + v;
    if (WRITE_BF16)
      OutB[obase] = __float2bfloat16(h);
    else
      OutF[obase] = h;
    obase += 256;
  }
  if (c == NCHUNK - 1) Hlast[b * 256 + d] = h;
}

// ---------------------------------------------------------------------------
extern "C" void kernel_launch(void* const* d_in, const int* in_sizes, int n_in,
                              void* d_out, int out_size, void* d_ws,
                              size_t ws_size, hipStream_t stream) {
  const float* x = (const float*)d_in[0];
  const float* W0f = (const float*)d_in[1];
  const float* b0 = (const float*)d_in[2];
  const float* W1f = (const float*)d_in[3];
  const float* b1 = (const float*)d_in[4];

  float* outF = (float*)d_out;              // out1 (f32), Mm*256 elements
  float* hlast = outF + (long)Mm * 256;     // h: (2,8,1,256) f32
  // d_out's first 32 MiB doubles as bf16 scratch for X1 (dead before the
  // final f32 out-write overwrites it; ordering is stream-sequential).
  bf16* X1b = (bf16*)d_out;

  char* ws = (char*)d_ws;
  unsigned* AV = (unsigned*)ws;                      // 4*Mm*64 u32 = 64 MiB
  bf16* W0b = (bf16*)(ws + (long)Mm * 256 * 4);      // 512*256 bf16
  bf16* W1b = W0b + (long)Nn * Dd;
  float2* AVs = (float2*)(W1b + (long)Nn * Dd);      // [Bb*NCHUNK][256] = 2 MiB

  const dim3 gemmGrid(2048);  // 1-D, XCD-bijective swizzle decoded in-kernel
  const dim3 blk(256);

  // Convert both weight matrices to bf16 in one launch
  const long n4w = (long)Nn * Dd / 4;
  cvt_weights<<<dim3((2 * n4w + 255) / 256), blk, 0, stream>>>(W0f, W1f, W0b,
                                                               W1b, n4w);

  // Layer 0 (A = f32 x, reg-staged, converted once at stage time)
  gemm_av_fused<true><<<gemmGrid, blk, 0, stream>>>(x, W0b, b0, AV, AVs);
  scan_final<true><<<dim3(Bb * NCHUNK), blk, 0, stream>>>(AV, AVs, X1b,
                                                          nullptr, hlast);

  // Layer 1 (A = bf16 X1 in d_out scratch)
  gemm_av_fused<false><<<gemmGrid, blk, 0, stream>>>(X1b, W1b, b1, AV, AVs);
  scan_final<false><<<dim3(Bb * NCHUNK), blk, 0, stream>>>(
      AV, AVs, nullptr, outF, hlast + Bb * 256);
}

// Round 6
// 242.161 us; speedup vs baseline: 1.2363x; 1.0922x over previous
//
#include <hip/hip_runtime.h>
#include <hip/hip_bf16.h>

// Problem constants
#define Bb 8
#define Ss 8192
#define Dd 256             // DIN == DH == 256
#define Mm (Bb * Ss)       // 65536 rows
#define Nn 512             // 2*DH output cols of the GEMM
#define NCHUNK 128
#define CLEN (Ss / NCHUNK) // 64
#define TSP 68             // Ts row stride (u32): 64 + 4 pad

typedef __hip_bfloat16 bf16;
typedef __attribute__((ext_vector_type(8))) short short8;
typedef __attribute__((ext_vector_type(4))) float f32x4;

// ---------------------------------------------------------------------------
// f32 -> bf16 convert, both weight matrices in one launch
// ---------------------------------------------------------------------------
__global__ __launch_bounds__(256) void cvt_weights(
    const float* __restrict__ inA, const float* __restrict__ inB,
    bf16* __restrict__ outA, bf16* __restrict__ outB, long n4each) {
  long i = (long)blockIdx.x * blockDim.x + threadIdx.x;
  const float* in = inA;
  bf16* out = outA;
  if (i >= n4each) {
    in = inB;
    out = outB;
    i -= n4each;
  }
  if (i >= n4each) return;
  const float4 v = ((const float4*)in)[i];
  union { ushort4 u; bf16 h[4]; } o;
  o.h[0] = __float2bfloat16(v.x);
  o.h[1] = __float2bfloat16(v.y);
  o.h[2] = __float2bfloat16(v.z);
  o.h[3] = __float2bfloat16(v.w);
  ((ushort4*)out)[i] = o.u;
}

// ---------------------------------------------------------------------------
// Pointwise: a = sigmoid(-gate), v = sigmoid(gate) * g(hidden)
// v7: divide-free, clamp-free (~14 VALU vs ~30).
//   exp overflow -> inf -> rcp -> 0 is exactly the right limit, so no clamps.
//   rcp rel-err ~1e-6 is invisible after bf16 packing (rel 2^-8).
// ---------------------------------------------------------------------------
__device__ __forceinline__ void av_from_gh(float gate, float hid, float& a,
                                           float& v) {
  const float eg = __expf(gate);
  a = __builtin_amdgcn_rcpf(1.f + eg);        // sigmoid(-gate) = 1 - z
  const float z = 1.f - a;                    // sigmoid(gate)
  const float eh = __expf(fminf(hid, 0.f));
  const float sig = eh * __builtin_amdgcn_rcpf(1.f + eh);
  const float gfun = (hid >= 0.f) ? (hid + 0.5f) : sig;
  v = z * gfun;
}

__device__ __forceinline__ unsigned pack_av(float a, float v) {
  union { bf16 h[2]; unsigned u; } o;
  o.h[0] = __float2bfloat16(a);
  o.h[1] = __float2bfloat16(v);
  return o.u;
}

// ---------------------------------------------------------------------------
// Fused GEMM + bias + pointwise + per-chunk scan summaries.
//
// v7 (= v6 K-loop, epilogue VALU cut):
//  * reg-staged global->VGPR->ds_write staging, one barrier per K-step,
//    2-step global lookahead (v6, best-known).
//  * av_from_gh divide/clamp-free (above).
//  * per-chunk summary parallelized over ALL 256 threads: 4 segments x
//    16 rows + ordered tree-combine through LDS (was: 64 threads x 64 rows
//    while 3 waves idled).
// ---------------------------------------------------------------------------
template <bool F32A>
__global__ __launch_bounds__(256, 3) void gemm_av_fused(
    const void* __restrict__ Xv, const bf16* __restrict__ W,
    const float* __restrict__ bias, unsigned* __restrict__ AV,
    float2* __restrict__ AVs) {
  __shared__ __align__(16) char sm[32768];
  bf16* Ab[2] = {(bf16*)sm, (bf16*)(sm + 8192)};
  bf16* Bbf[2] = {(bf16*)(sm + 16384), (bf16*)(sm + 24576)};
  unsigned* Ts = (unsigned*)sm;            // post-K overlay: [64 t][TSP] u32
  float2* Ps = (float2*)(sm + 20480);      // summary partials: [4 seg][64 d]

  const int tid = threadIdx.x;
  const int w = tid >> 6;
  const int l = tid & 63;
  const int fl = l & 15;
  const int q = l >> 4;

  // XCD-bijective swizzle: xcd owns lin [xcd*256,+256) = bt in [xcd*64,+64)
  const int id = blockIdx.x;
  const int lin = ((id & 7) << 8) | (id >> 3);
  const int cb = lin & 3;              // paired-channel block 0..3
  const int bt = lin >> 2;             // M-tile 0..511
  const long rowBase = (long)bt * 128;
  const int wrow = (w >> 1) * 64;
  const int wc = (w & 1) * 32;

  const float* Xf = (const float*)Xv;
  const bf16* Xb = (const bf16*)Xv;

  // ---- staging addresses (hoisted). Thread covers 2 (row,kq) slots:
  //      idx = c*256+tid -> row = idx>>2 (0..127), kq = idx&3 (8-bf16 chunk).
  //      LDS layout [row][32 k], chunk swizzled: kq' = kq ^ ((row>>1)&3).
  const float* aSF[2];
  const bf16* aSB[2];
  const bf16* bS[2];
  int ldsOff[2];
#pragma unroll
  for (int c = 0; c < 2; c++) {
    const int idx = c * 256 + tid;
    const int row = idx >> 2;
    const int kq = idx & 3;
    ldsOff[c] = row * 32 + (kq ^ ((row >> 1) & 3)) * 8;
    aSF[c] = Xf + (rowBase + row) * 256 + kq * 8;
    aSB[c] = Xb + (rowBase + row) * 256 + kq * 8;
    const int grow = (row < 64) ? (cb * 64 + row) : (192 + cb * 64 + row);
    bS[c] = W + (long)grow * 256 + kq * 8;
  }

  // staging registers (tile in flight)
  short8 aReg[2], bReg[2];
  float4 aF[2][2];

  auto loadG = [&](int ks) {
    if constexpr (F32A) {
#pragma unroll
      for (int c = 0; c < 2; c++) {
        aF[c][0] = *(const float4*)(aSF[c] + ks * 32);
        aF[c][1] = *(const float4*)(aSF[c] + ks * 32 + 4);
      }
    } else {
#pragma unroll
      for (int c = 0; c < 2; c++)
        aReg[c] = *(const short8*)(aSB[c] + ks * 32);
    }
#pragma unroll
    for (int c = 0; c < 2; c++)
      bReg[c] = *(const short8*)(bS[c] + ks * 32);
  };
  auto writeL = [&](int bi) {
#pragma unroll
    for (int c = 0; c < 2; c++) {
      short8 av_;
      if constexpr (F32A) {
        const float vals[8] = {aF[c][0].x, aF[c][0].y, aF[c][0].z, aF[c][0].w,
                               aF[c][1].x, aF[c][1].y, aF[c][1].z, aF[c][1].w};
#pragma unroll
        for (int i = 0; i < 8; i++) {
          union { bf16 h; short s; } t;
          t.h = __float2bfloat16(vals[i]);
          av_[i] = t.s;
        }
      } else {
        av_ = aReg[c];
      }
      *(short8*)(Ab[bi] + ldsOff[c]) = av_;
    }
#pragma unroll
    for (int c = 0; c < 2; c++)
      *(short8*)(Bbf[bi] + ldsOff[c]) = bReg[c];
  };

  // ---- fragment LDS offsets (hoisted, swizzle-matched, conflict-free)
  int aOff[4], bOff[4];
#pragma unroll
  for (int mt = 0; mt < 4; mt++) {
    const int row = wrow + 16 * mt + fl;
    aOff[mt] = row * 32 + (q ^ ((row >> 1) & 3)) * 8;
  }
#pragma unroll
  for (int nt = 0; nt < 4; nt++) {
    const int row =
        (nt < 2) ? (wc + 16 * nt + fl) : (64 + wc + 16 * (nt - 2) + fl);
    bOff[nt] = row * 32 + (q ^ ((row >> 1) & 3)) * 8;
  }

  f32x4 acc[4][4];
#pragma unroll
  for (int i = 0; i < 4; i++)
#pragma unroll
    for (int j = 0; j < 4; j++) acc[i][j] = (f32x4)0.0f;

  // ---- K-loop: reg-staged, ONE barrier per step (v6, best-known).
  loadG(0);
  writeL(0);
  loadG(1);
  __syncthreads();
#pragma unroll
  for (int ks = 0; ks < 8; ks++) {
    const int bi = ks & 1;
    short8 af[4], bf_[4];
#pragma unroll
    for (int mt = 0; mt < 4; mt++)
      af[mt] = *(const short8*)(Ab[bi] + aOff[mt]);
#pragma unroll
    for (int nt = 0; nt < 4; nt++)
      bf_[nt] = *(const short8*)(Bbf[bi] + bOff[nt]);
    if (ks < 7) writeL(bi ^ 1);   // tile ks+1 -> other buffer
    if (ks < 6) loadG(ks + 2);    // issue next-next tile's global loads
#pragma unroll
    for (int mt = 0; mt < 4; mt++)
#pragma unroll
      for (int nt = 0; nt < 4; nt++)
        acc[mt][nt] = __builtin_amdgcn_mfma_f32_16x16x32_bf16(
            af[mt], bf_[nt], acc[mt][nt], 0, 0, 0);
    asm volatile("s_waitcnt lgkmcnt(0)" ::: "memory");
    __builtin_amdgcn_s_barrier();
  }

  // ---- Epilogue: bias + pointwise + pack (registers only)
  float bg[2], bh[2];
#pragma unroll
  for (int p = 0; p < 2; p++) {
    const int d = cb * 64 + wc + 16 * p + fl;
    bg[p] = bias[d];
    bh[p] = bias[256 + d];
  }
  unsigned pk[4][2][4];
#pragma unroll
  for (int mt = 0; mt < 4; mt++)
#pragma unroll
    for (int p = 0; p < 2; p++)
#pragma unroll
      for (int r = 0; r < 4; r++) {
        float a, v;
        av_from_gh(acc[mt][p][r] + bg[p], acc[mt][p + 2][r] + bh[p], a, v);
        pk[mt][p][r] = pack_av(a, v);
      }

  // ---- Two 64-row halves through LDS transpose:
  //      dense coalesced AV stores + all-thread per-chunk scan summaries
#pragma unroll
  for (int h = 0; h < 2; h++) {
    if ((w >> 1) == h) {
#pragma unroll
      for (int mt = 0; mt < 4; mt++)
#pragma unroll
        for (int p = 0; p < 2; p++)
#pragma unroll
          for (int r = 0; r < 4; r++)
            Ts[(16 * mt + 4 * q + r) * TSP + wc + 16 * p + fl] = pk[mt][p][r];
    }
    __syncthreads();
    // dense AV half-tile: [64 rows][64 d] u32 -> 1KB/wave contiguous stores
    {
      unsigned* dst = AV + ((long)cb * Mm + rowBase + h * 64) * 64;
#pragma unroll
      for (int j = 0; j < 4; j++) {
        const int idx = j * 256 + tid;
        const int t = idx >> 4;
        const int d4 = idx & 15;
        const uint4 val = *(const uint4*)(Ts + t * TSP + d4 * 4);
        *(uint4*)(dst + 4 * idx) = val;
      }
    }
    // summary partials: thread (sg, dl) folds rows [sg*16, +16) of column dl
    {
      const int dl = tid & 63;
      const int sg = tid >> 6;
      float A = 1.f, H = 0.f;
#pragma unroll
      for (int t = 0; t < 16; t++) {
        const unsigned p = Ts[(sg * 16 + t) * TSP + dl];
        const float a = __uint_as_float((p & 0xffffu) << 16);
        const float v = __uint_as_float(p & 0xffff0000u);
        A *= a;
        H = a * H + v;
      }
      Ps[sg * 64 + dl] = make_float2(A, H);
    }
    __syncthreads();
    if (tid < 64) {
      float2 r = Ps[tid];  // segment 0
#pragma unroll
      for (int s = 1; s < 4; s++) {
        const float2 n = Ps[s * 64 + tid];
        r = make_float2(r.x * n.x, n.x * r.y + n.y);  // apply seg s after r
      }
      const long cg = (long)(bt >> 6) * NCHUNK + ((bt & 63) << 1) + h;
      AVs[cg * 256 + cb * 64 + tid] = r;
    }
    __syncthreads();
  }
}

// ---------------------------------------------------------------------------
// Final scan. Prologue folds this chunk's prefix from the (L3-hot, 2MB)
// chunk-summary table (independent loads). WRITE_BF16 ? bf16 : f32 stream.
// AV layout: [cb 4][row][64 d] u32 (matches gemm's dense writes).
// ---------------------------------------------------------------------------
template <bool WRITE_BF16>
__global__ __launch_bounds__(256) void scan_final(
    const unsigned* __restrict__ AV, const float2* __restrict__ AVs,
    bf16* __restrict__ OutB, float* __restrict__ OutF,
    float* __restrict__ Hlast) {
  const int d = threadIdx.x;
  const int c = blockIdx.x % NCHUNK;
  const int b = blockIdx.x / NCHUNK;

  float h = 0.5f;  // h0 = g(0) = 0.5
#pragma unroll 4
  for (int j = 0; j < c; j++) {
    const float2 av = AVs[((long)b * NCHUNK + j) * 256 + d];
    h = av.x * h + av.y;
  }

  const long row0 = (long)b * Ss + (long)c * CLEN;
  const unsigned* src = AV + (long)(d >> 6) * Mm * 64 + (d & 63);
  long obase = row0 * 256 + d;
#pragma unroll 8
  for (int t = 0; t < CLEN; t++) {
    const unsigned p = src[(row0 + t) * 64];
    const float a = __uint_as_float((p & 0xffffu) << 16);
    const float v = __uint_as_float(p & 0xffff0000u);
    h = a * h + v;
    if (WRITE_BF16)
      OutB[obase] = __float2bfloat16(h);
    else
      OutF[obase] = h;
    obase += 256;
  }
  if (c == NCHUNK - 1) Hlast[b * 256 + d] = h;
}

// ---------------------------------------------------------------------------
extern "C" void kernel_launch(void* const* d_in, const int* in_sizes, int n_in,
                              void* d_out, int out_size, void* d_ws,
                              size_t ws_size, hipStream_t stream) {
  const float* x = (const float*)d_in[0];
  const float* W0f = (const float*)d_in[1];
  const float* b0 = (const float*)d_in[2];
  const float* W1f = (const float*)d_in[3];
  const float* b1 = (const float*)d_in[4];

  float* outF = (float*)d_out;              // out1 (f32), Mm*256 elements
  float* hlast = outF + (long)Mm * 256;     // h: (2,8,1,256) f32
  // d_out's first 32 MiB doubles as bf16 scratch for X1 (dead before the
  // final f32 out-write overwrites it; ordering is stream-sequential).
  bf16* X1b = (bf16*)d_out;

  char* ws = (char*)d_ws;
  unsigned* AV = (unsigned*)ws;                      // 4*Mm*64 u32 = 64 MiB
  bf16* W0b = (bf16*)(ws + (long)Mm * 256 * 4);      // 512*256 bf16
  bf16* W1b = W0b + (long)Nn * Dd;
  float2* AVs = (float2*)(W1b + (long)Nn * Dd);      // [Bb*NCHUNK][256] = 2 MiB

  const dim3 gemmGrid(2048);  // 1-D, XCD-bijective swizzle decoded in-kernel
  const dim3 blk(256);

  // Convert both weight matrices to bf16 in one launch
  const long n4w = (long)Nn * Dd / 4;
  cvt_weights<<<dim3((2 * n4w + 255) / 256), blk, 0, stream>>>(W0f, W1f, W0b,
                                                               W1b, n4w);

  // Layer 0 (A = f32 x, reg-staged, converted once at stage time)
  gemm_av_fused<true><<<gemmGrid, blk, 0, stream>>>(x, W0b, b0, AV, AVs);
  scan_final<true><<<dim3(Bb * NCHUNK), blk, 0, stream>>>(AV, AVs, X1b,
                                                          nullptr, hlast);

  // Layer 1 (A = bf16 X1 in d_out scratch)
  gemm_av_fused<false><<<gemmGrid, blk, 0, stream>>>(X1b, W1b, b1, AV, AVs);
  scan_final<false><<<dim3(Bb * NCHUNK), blk, 0, stream>>>(
      AV, AVs, nullptr, outF, hlast + Bb * 256);
}